// Round 3
// baseline (316.096 us; speedup 1.0000x reference)
//
#include <hip/hip_runtime.h>
#include <hip/hip_bf16.h>

// ViT attention, MFMA bf16 pipeline. B=16, N=1024, C=768, H=12, D=64.
// Round 8: round-7 32x32 structure with the softmax path de-asm'd (bisect):
//  - exp via exp2f() (native v_exp_f32), Q pre-scaled by 0.125*log2e.
//  - bf16 pair pack via scalar converts + shift/or (round-6 proven).
//  - half-wave P exchange via __shfl_xor(32) + select (guaranteed semantics)
//    instead of raw-asm v_permlane32_swap_b32 (prime suspect for round-7's
//    absmax 0.106 = half-scrambled key->V pairing).
//  - launch_bounds (256,3): 170 VGPR budget, no spill risk.
// Structure: S^T = K*Q^T in 32x32 MFMA; lane's 16 C-regs all belong to ONE
// q row (col=lane&31) -> lane-local row-sum, in-register P assembly, no P LDS.
// LDS 32 KB/block (K,V double-buffered only).
// MFMA 32x32x16 bf16 layouts (m74/m101):
//   A-op: lane holds A[m=lane&31][k=8*(lane>>5)+j]
//   B-op: lane holds B[k=8*(lane>>5)+j][n=lane&31]
//   C/D : reg r = D[row=(r&3)+8*(r>>2)+4*(lane>>5)][col=lane&31]

typedef __attribute__((ext_vector_type(8))) short short8;
typedef __attribute__((ext_vector_type(4))) float floatx4;
typedef __attribute__((ext_vector_type(16))) float floatx16;

constexpr int Bsz = 16, Nseq = 1024, Cdim = 768, Hh = 12, Dd = 64;
constexpr float SCALE = 0.125f;            // 64^-0.5
constexpr float QSC = 0.1803368801f;       // SCALE * log2(e), folded into Q

__device__ __forceinline__ ushort f2bs(float f) {
    union { __hip_bfloat16 h; ushort u; } cv;
    cv.h = __float2bfloat16(f);
    return cv.u;
}
__device__ __forceinline__ void stF(float* p, float v) { *p = v; }
__device__ __forceinline__ void stF(ushort* p, float v) { *p = f2bs(v); }

// async 16B/lane global->LDS DMA. lds must be wave-uniform; HW adds lane*16.
__device__ __forceinline__ void gld16(void* lds, const void* g) {
    __builtin_amdgcn_global_load_lds(
        (const __attribute__((address_space(1))) unsigned int*)g,
        (__attribute__((address_space(3))) unsigned int*)lds, 16, 0, 0);
}

// fp32 -> bf16 pack: x | qkv_w | proj_w
__global__ __launch_bounds__(256) void pack_bf16(
        const float* __restrict__ x, const float* __restrict__ w1,
        const float* __restrict__ w2, ushort* __restrict__ xb,
        ushort* __restrict__ w1b, ushort* __restrict__ w2b) {
    const size_t n0 = (size_t)Bsz * Nseq * Cdim;   // 12,582,912
    const size_t n1 = (size_t)3 * Cdim * Cdim;     //  1,769,472
    size_t i = ((size_t)blockIdx.x * 256 + threadIdx.x) * 4;
    const float* src;
    ushort* dst;
    if (i < n0) { src = x; dst = xb; }
    else if (i < n0 + n1) { i -= n0; src = w1; dst = w1b; }
    else { i -= n0 + n1; src = w2; dst = w2b; }
    float4 v = *(const float4*)&src[i];
    *(ushort4*)&dst[i] = make_ushort4(f2bs(v.x), f2bs(v.y), f2bs(v.z), f2bs(v.w));
}

// C = A[M,K] @ Bw[N,K]^T + bias[N]. 128x128 tile, BK=64, 256 thr, 4 waves.
// Cols >= split written transposed to vt when vmode (per-head V^T).
// Cols < qsplit scaled by qscale (SCALE*log2e folding for Q).
template <typename TO>
__global__ __launch_bounds__(256) void gemm_nt_mfma(
        const ushort* __restrict__ A, const ushort* __restrict__ Bw,
        const float* __restrict__ bias, TO* __restrict__ C0,
        ushort* __restrict__ vt, int split, int ld0,
        int M, int N, int K, int vmode, int qsplit, float qscale) {
    __shared__ ushort As[128 * 64];   // [row][k] unpadded, XOR-8 swizzled
    __shared__ ushort Bs[128 * 64];
    const int t = threadIdx.x;
    const int lane = t & 63;
    const int w = t >> 6;
    const int quad = lane >> 4;
    const int l16 = lane & 15;
    const int m0 = blockIdx.y * 128;
    const int n0 = blockIdx.x * 128;
    const int mw = (w >> 1) * 64;
    const int nw = (w & 1) * 64;
    const int srow = lane >> 3;
    const int schunk = lane & 7;

    floatx4 acc[4][4];
#pragma unroll
    for (int i = 0; i < 4; ++i)
#pragma unroll
        for (int j = 0; j < 4; ++j) acc[i][j] = (floatx4)0.0f;

    for (int k0 = 0; k0 < K; k0 += 64) {
        __syncthreads();
#pragma unroll
        for (int i = 0; i < 4; ++i) {
            int r0 = (w * 4 + i) * 8;
            int row = r0 + srow;
            int cs = (schunk ^ (row & 7)) * 8;
            gld16(&As[r0 * 64], &A[(size_t)(m0 + row) * K + k0 + cs]);
            gld16(&Bs[r0 * 64], &Bw[(size_t)(n0 + row) * K + k0 + cs]);
        }
        __syncthreads();

#pragma unroll
        for (int kk = 0; kk < 2; ++kk) {
            const int pc = ((kk * 4 + quad) ^ (l16 & 7)) * 8;
            short8 af[4], bfr[4];
#pragma unroll
            for (int i = 0; i < 4; ++i)
                af[i] = *(const short8*)&As[(mw + i * 16 + l16) * 64 + pc];
#pragma unroll
            for (int j = 0; j < 4; ++j)
                bfr[j] = *(const short8*)&Bs[(nw + j * 16 + l16) * 64 + pc];
#pragma unroll
            for (int i = 0; i < 4; ++i)
#pragma unroll
                for (int j = 0; j < 4; ++j)
                    acc[i][j] = __builtin_amdgcn_mfma_f32_16x16x32_bf16(
                        af[i], bfr[j], acc[i][j], 0, 0, 0);
        }
    }

#pragma unroll
    for (int j = 0; j < 4; ++j) {
        int col = n0 + nw + j * 16 + l16;
        float bc = bias[col];
        float sc = (col < qsplit) ? qscale : 1.0f;
        if (vmode && col >= split) {
            int ch = col - split;
            int h = ch >> 6, d = ch & 63;
#pragma unroll
            for (int i = 0; i < 4; ++i)
#pragma unroll
                for (int r = 0; r < 4; ++r) {
                    int row = m0 + mw + i * 16 + quad * 4 + r;
                    int b = row >> 10, n = row & 1023;
                    vt[(((size_t)(b * Hh + h)) * Dd + d) * Nseq + n] =
                        f2bs(acc[i][j][r] + bc);
                }
        } else {
#pragma unroll
            for (int i = 0; i < 4; ++i)
#pragma unroll
                for (int r = 0; r < 4; ++r) {
                    int row = m0 + mw + i * 16 + quad * 4 + r;
                    stF(&C0[(size_t)row * ld0 + col], (acc[i][j][r] + bc) * sc);
                }
        }
    }
}

// Flash attention, no-max softmax, S^T formulation, 32x32x16 MFMA,
// in-register P (shfl_xor half-exchange), no P LDS.
// Block = (b,h, 128-q tile), 4 waves; wave w owns q rows w*32..w*32+31.
// KV tiles of 64, double-buffered staging.
__global__ __launch_bounds__(256, 3) void attn_mfma(
        const ushort* __restrict__ qk, const ushort* __restrict__ vt,
        ushort* __restrict__ outp) {
    __shared__ ushort Ks[2][64 * 64];   // [key][d], XOR-8 swizzled
    __shared__ ushort Vts[2][64 * 64];  // [d][key], XOR-8 swizzled

    const int t = threadIdx.x;
    const int lane = t & 63;
    const int w = t >> 6;
    const int l32 = lane & 31;
    const int hi = lane >> 5;
    const int srow = lane >> 3;
    const int schunk = lane & 7;

    // XCD swizzle: 8 q-tiles of one bh land on one XCD, consecutively.
    const int bid = blockIdx.x;
    const int qt = (bid >> 3) & 7;
    const int bh = (bid & 7) + 8 * (bid >> 6);
    const int h = bh % Hh, b = bh / Hh;

    const size_t rs = 2 * Cdim;  // 1536
    const ushort* qbase = qk + (size_t)b * Nseq * rs + h * Dd;
    const ushort* kbase = qbase + Cdim;
    const ushort* vbase = vt + (size_t)bh * Dd * Nseq;

    // Q fragments in registers (pre-scaled by SCALE*log2e at gemm1).
    // B-op for S^T: lane holds Q[q=l32][d=kc*16+hi*8+j]
    short8 aq[4];
    {
        int q = qt * 128 + w * 32 + l32;
#pragma unroll
        for (int kc = 0; kc < 4; ++kc)
            aq[kc] = *(const short8*)&qbase[(size_t)q * rs + kc * 16 + hi * 8];
    }

    auto stage = [&](int kt64, int buf) {
#pragma unroll
        for (int i = 0; i < 2; ++i) {
            int r0 = (w * 2 + i) * 8;
            int row = r0 + srow;
            int cs = (schunk ^ (row & 7)) * 8;
            gld16(&Ks[buf][r0 * 64], &kbase[(size_t)(kt64 * 64 + row) * rs + cs]);
            gld16(&Vts[buf][r0 * 64], &vbase[(size_t)row * Nseq + kt64 * 64 + cs]);
        }
    };

    floatx16 o[2];
    o[0] = (floatx16)0.0f;
    o[1] = (floatx16)0.0f;
    float lsum = 0.f;

    stage(0, 0);
    for (int kt = 0; kt < Nseq / 64; ++kt) {
        __syncthreads();  // drains DMA for tile kt; guards buf reuse
        if (kt + 1 < Nseq / 64) stage(kt + 1, (kt + 1) & 1);
        const ushort* Kb = Ks[kt & 1];
        const ushort* Vb = Vts[kt & 1];

        // S^T = K Q^T : st[km] reg r = S^T[key=km*32+(r&3)+8*(r>>2)+4*hi][q=l32]
        floatx16 st[2];
        st[0] = (floatx16)0.0f;
        st[1] = (floatx16)0.0f;
#pragma unroll
        for (int kc = 0; kc < 4; ++kc) {
            const int cs = ((kc * 2 + hi) ^ (l32 & 7)) * 8;
            short8 ak0 = *(const short8*)&Kb[l32 * 64 + cs];
            short8 ak1 = *(const short8*)&Kb[(32 + l32) * 64 + cs];
            st[0] = __builtin_amdgcn_mfma_f32_32x32x16_bf16(ak0, aq[kc], st[0], 0, 0, 0);
            st[1] = __builtin_amdgcn_mfma_f32_32x32x16_bf16(ak1, aq[kc], st[1], 0, 0, 0);
        }

#pragma unroll
        for (int km = 0; km < 2; ++km) {
            // p = 2^s (Q pre-scaled by log2e); all 16 values belong to q=l32.
            // key(p[r]) = km*32 + (r&3) + 8*(r>>2) + 4*hi
            float p[16];
#pragma unroll
            for (int r = 0; r < 16; ++r) p[r] = exp2f(st[km][r]);
            lsum += (((p[0] + p[1]) + (p[2] + p[3])) +
                     ((p[4] + p[5]) + (p[6] + p[7]))) +
                    (((p[8] + p[9]) + (p[10] + p[11])) +
                     ((p[12] + p[13]) + (p[14] + p[15])));
            // pack consecutive-key pairs: c[i] = bf16(p[2i]) | bf16(p[2i+1])<<16
            // keys(c[i]): i=0:(0,1)+4hi  1:(2,3)+4hi  2:(8,9)+4hi  3:(10,11)+4hi
            //             4:(16,17)+4hi 5:(18,19)+4hi 6:(24,25)+4hi 7:(26,27)+4hi
            uint c[8];
#pragma unroll
            for (int i = 0; i < 8; ++i)
                c[i] = (uint)f2bs(p[2 * i]) | ((uint)f2bs(p[2 * i + 1]) << 16);
            // half-wave exchange via shfl_xor(32): A-frag word jw must hold
            // keys (8hi+2jw, 8hi+2jw+1) -> lo-half words from own c0/c1 +
            // partner c0/c1; hi-half words from partner c2/c3 + own c2/c3.
            uint x0 = __shfl_xor(c[0], 32), x1 = __shfl_xor(c[1], 32);
            uint x2 = __shfl_xor(c[2], 32), x3 = __shfl_xor(c[3], 32);
            union { uint u[4]; short8 s; } af0, af1;
            af0.u[0] = hi ? x2 : c[0];
            af0.u[1] = hi ? x3 : c[1];
            af0.u[2] = hi ? c[2] : x0;
            af0.u[3] = hi ? c[3] : x1;
            uint x4 = __shfl_xor(c[4], 32), x5 = __shfl_xor(c[5], 32);
            uint x6 = __shfl_xor(c[6], 32), x7 = __shfl_xor(c[7], 32);
            af1.u[0] = hi ? x6 : c[4];
            af1.u[1] = hi ? x7 : c[5];
            af1.u[2] = hi ? c[6] : x4;
            af1.u[3] = hi ? c[7] : x5;

            // O[q][d] += P V : B-op = V[key][d=l32+dblk*32] from Vts[d][key]
#pragma unroll
            for (int dblk = 0; dblk < 2; ++dblk) {
                const int row = dblk * 32 + l32;
#pragma unroll
                for (int ks = 0; ks < 2; ++ks) {
                    const int ch = ((km * 4 + ks * 2 + hi) ^ (l32 & 7)) * 8;
                    short8 bv = *(const short8*)&Vb[row * 64 + ch];
                    o[dblk] = __builtin_amdgcn_mfma_f32_32x32x16_bf16(
                        ks ? af1.s : af0.s, bv, o[dblk], 0, 0, 0);
                }
            }
        }
    }

    // full row-sum: partner half-wave holds the other 32 keys per tile
    float lf = lsum + __shfl_xor(lsum, 32);
    float linv = __builtin_amdgcn_rcpf(lf);

    // O C-layout: col = d = l32 (+dblk*32), row = q = (r&3)+8*(r>>2)+4*hi
    const int qg0 = qt * 128 + w * 32;
#pragma unroll
    for (int r = 0; r < 16; ++r) {
        int rowq = (r & 3) + 8 * (r >> 2) + 4 * hi;
        float li = __shfl(linv, rowq);
        int q = qg0 + rowq;
#pragma unroll
        for (int dblk = 0; dblk < 2; ++dblk) {
            int d = dblk * 32 + l32;
            outp[((size_t)(b * Nseq + q)) * Cdim + h * Dd + d] =
                f2bs(o[dblk][r] * li);
        }
    }
}

extern "C" void kernel_launch(void* const* d_in, const int* in_sizes, int n_in,
                              void* d_out, int out_size, void* d_ws, size_t ws_size,
                              hipStream_t stream) {
    const float* x      = (const float*)d_in[0];
    const float* qkv_w  = (const float*)d_in[1];
    const float* qkv_b  = (const float*)d_in[2];
    const float* proj_w = (const float*)d_in[3];
    const float* proj_b = (const float*)d_in[4];
    float* out = (float*)d_out;

    const int M = Bsz * Nseq;  // 16384
    ushort* xb    = (ushort*)d_ws;                        // [16384x768]
    ushort* qk    = xb + (size_t)M * Cdim;                // [16384x1536]
    ushort* vtbuf = qk + (size_t)M * 2 * Cdim;            // [192][64][1024]
    ushort* wqkvb = vtbuf + (size_t)Hh * Bsz * Dd * Nseq; // [2304x768]
    ushort* wprjb = wqkvb + (size_t)3 * Cdim * Cdim;      // [768x768]
    ushort* attnout = xb;  // xb dead after gemm1

    // 0) fp32 -> bf16 pack
    pack_bf16<<<14592, 256, 0, stream>>>(x, qkv_w, proj_w, xb, wqkvb, wprjb);
    // 1) qkv GEMM: Q (cols<768, pre-scaled by SCALE*log2e) + K -> qk; V -> vt^T
    gemm_nt_mfma<ushort><<<dim3(18, 128), 256, 0, stream>>>(
        xb, wqkvb, qkv_b, qk, vtbuf, 2 * Cdim, 2 * Cdim, M, 3 * Cdim, Cdim, 1,
        Cdim, QSC);
    // 2) attention
    attn_mfma<<<Bsz * Hh * (Nseq / 128), 256, 0, stream>>>(qk, vtbuf, attnout);
    // 3) projection -> fp32 out
    gemm_nt_mfma<float><<<dim3(6, 128), 256, 0, stream>>>(
        attnout, wprjb, proj_b, out, vtbuf, 1 << 30, Cdim, M, Cdim, Cdim, 0,
        0, 1.0f);
}

// Round 4
// 299.326 us; speedup vs baseline: 1.0560x; 1.0560x over previous
//
#include <hip/hip_runtime.h>
#include <hip/hip_bf16.h>

// ViT attention, MFMA bf16 pipeline. B=16, N=1024, C=768, H=12, D=64.
// Round 9:
//  - attn softmax de-fattened: raw v_exp_f32 via __builtin_amdgcn_exp2f
//    (exp2f() library fixup was the round-8 regression), pair-pack via
//    __float22bfloat162_rn (1x v_cvt_pk_bf16_f32), half-wave P exchange via
//    __builtin_amdgcn_permlane32_swap (8 VALU ops vs 16 ds_bpermute+16 sel).
//  - V^T computed as a GEMM output (VT-gemm: Wv[768x768] @ X^T -> [768][16384],
//    bias-per-row, coalesced stores) replacing gemm1's 2B-scatter epilogue.
//  - gemm1 now QK only (N=1536); attn reads vt with ld=16384.
// Structure: S^T = K*Q^T in 32x32 MFMA; lane's 16 C-regs all belong to ONE
// q row (col=lane&31) -> lane-local row-sum, in-register P assembly, no P LDS.
// LDS 32 KB/block attn (K,V double-buffered only).
// MFMA 32x32x16 bf16 layouts (m74/m101):
//   A-op: lane holds A[m=lane&31][k=8*(lane>>5)+j]
//   B-op: lane holds B[k=8*(lane>>5)+j][n=lane&31]
//   C/D : reg r = D[row=(r&3)+8*(r>>2)+4*(lane>>5)][col=lane&31]
// permlane32_swap(v0,v1): r.x = {v0.lo32lanes, v1.lo32lanes},
//                         r.y = {v0.hi32lanes, v1.hi32lanes}  (ISA: swap
//                         vdst lanes32-63 with src lanes0-31; both returned)

typedef __attribute__((ext_vector_type(8))) short short8;
typedef __attribute__((ext_vector_type(4))) float floatx4;
typedef __attribute__((ext_vector_type(16))) float floatx16;
typedef __attribute__((ext_vector_type(2))) unsigned int uint2v;

constexpr int Bsz = 16, Nseq = 1024, Cdim = 768, Hh = 12, Dd = 64;
constexpr float QSC = 0.1803368801f;       // 64^-0.5 * log2(e), folded into Q
constexpr int LDV = Bsz * Nseq;            // 16384, vt leading dim

__device__ __forceinline__ ushort f2bs(float f) {
    union { __hip_bfloat16 h; ushort u; } cv;
    cv.h = __float2bfloat16(f);
    return cv.u;
}
__device__ __forceinline__ void stF(float* p, float v) { *p = v; }
__device__ __forceinline__ void stF(ushort* p, float v) { *p = f2bs(v); }

__device__ __forceinline__ float fexp2(float x) {
#if __has_builtin(__builtin_amdgcn_exp2f)
    return __builtin_amdgcn_exp2f(x);   // raw v_exp_f32; inputs |x|<~40, safe
#else
    return exp2f(x);
#endif
}

// async 16B/lane global->LDS DMA. lds must be wave-uniform; HW adds lane*16.
__device__ __forceinline__ void gld16(void* lds, const void* g) {
    __builtin_amdgcn_global_load_lds(
        (const __attribute__((address_space(1))) unsigned int*)g,
        (__attribute__((address_space(3))) unsigned int*)lds, 16, 0, 0);
}

// fp32 -> bf16 pack: x | qkv_w | proj_w
__global__ __launch_bounds__(256) void pack_bf16(
        const float* __restrict__ x, const float* __restrict__ w1,
        const float* __restrict__ w2, ushort* __restrict__ xb,
        ushort* __restrict__ w1b, ushort* __restrict__ w2b) {
    const size_t n0 = (size_t)Bsz * Nseq * Cdim;   // 12,582,912
    const size_t n1 = (size_t)3 * Cdim * Cdim;     //  1,769,472
    size_t i = ((size_t)blockIdx.x * 256 + threadIdx.x) * 4;
    const float* src;
    ushort* dst;
    if (i < n0) { src = x; dst = xb; }
    else if (i < n0 + n1) { i -= n0; src = w1; dst = w1b; }
    else { i -= n0 + n1; src = w2; dst = w2b; }
    float4 v = *(const float4*)&src[i];
    *(ushort4*)&dst[i] = make_ushort4(f2bs(v.x), f2bs(v.y), f2bs(v.z), f2bs(v.w));
}

// C = A[M,K] @ Bw[N,K]^T + bias. 128x128 tile, BK=64, 256 thr, 4 waves.
// bias_row ? bias[row] : bias[col]. Cols < qsplit scaled by qscale.
template <typename TO>
__global__ __launch_bounds__(256) void gemm_nt_mfma(
        const ushort* __restrict__ A, const ushort* __restrict__ Bw,
        const float* __restrict__ bias, TO* __restrict__ C0,
        int ld0, int M, int N, int K, int bias_row, int qsplit, float qscale) {
    __shared__ ushort As[128 * 64];   // [row][k] unpadded, XOR-8 swizzled
    __shared__ ushort Bs[128 * 64];
    const int t = threadIdx.x;
    const int lane = t & 63;
    const int w = t >> 6;
    const int quad = lane >> 4;
    const int l16 = lane & 15;
    const int m0 = blockIdx.y * 128;
    const int n0 = blockIdx.x * 128;
    const int mw = (w >> 1) * 64;
    const int nw = (w & 1) * 64;
    const int srow = lane >> 3;
    const int schunk = lane & 7;

    floatx4 acc[4][4];
#pragma unroll
    for (int i = 0; i < 4; ++i)
#pragma unroll
        for (int j = 0; j < 4; ++j) acc[i][j] = (floatx4)0.0f;

    for (int k0 = 0; k0 < K; k0 += 64) {
        __syncthreads();
#pragma unroll
        for (int i = 0; i < 4; ++i) {
            int r0 = (w * 4 + i) * 8;
            int row = r0 + srow;
            int cs = (schunk ^ (row & 7)) * 8;
            gld16(&As[r0 * 64], &A[(size_t)(m0 + row) * K + k0 + cs]);
            gld16(&Bs[r0 * 64], &Bw[(size_t)(n0 + row) * K + k0 + cs]);
        }
        __syncthreads();

#pragma unroll
        for (int kk = 0; kk < 2; ++kk) {
            const int pc = ((kk * 4 + quad) ^ (l16 & 7)) * 8;
            short8 af[4], bfr[4];
#pragma unroll
            for (int i = 0; i < 4; ++i)
                af[i] = *(const short8*)&As[(mw + i * 16 + l16) * 64 + pc];
#pragma unroll
            for (int j = 0; j < 4; ++j)
                bfr[j] = *(const short8*)&Bs[(nw + j * 16 + l16) * 64 + pc];
#pragma unroll
            for (int i = 0; i < 4; ++i)
#pragma unroll
                for (int j = 0; j < 4; ++j)
                    acc[i][j] = __builtin_amdgcn_mfma_f32_16x16x32_bf16(
                        af[i], bfr[j], acc[i][j], 0, 0, 0);
        }
    }

    if (bias_row) {
        float brv[4][4];
#pragma unroll
        for (int i = 0; i < 4; ++i)
#pragma unroll
            for (int r = 0; r < 4; ++r)
                brv[i][r] = bias[m0 + mw + i * 16 + quad * 4 + r];
#pragma unroll
        for (int j = 0; j < 4; ++j) {
            int col = n0 + nw + j * 16 + l16;
#pragma unroll
            for (int i = 0; i < 4; ++i)
#pragma unroll
                for (int r = 0; r < 4; ++r) {
                    int row = m0 + mw + i * 16 + quad * 4 + r;
                    stF(&C0[(size_t)row * ld0 + col], acc[i][j][r] + brv[i][r]);
                }
        }
    } else {
#pragma unroll
        for (int j = 0; j < 4; ++j) {
            int col = n0 + nw + j * 16 + l16;
            float bc = bias[col];
            float sc = (col < qsplit) ? qscale : 1.0f;
#pragma unroll
            for (int i = 0; i < 4; ++i)
#pragma unroll
                for (int r = 0; r < 4; ++r) {
                    int row = m0 + mw + i * 16 + quad * 4 + r;
                    stF(&C0[(size_t)row * ld0 + col], (acc[i][j][r] + bc) * sc);
                }
        }
    }
}

// Flash attention, no-max softmax, S^T formulation, 32x32x16 MFMA,
// in-register P (permlane32_swap half-exchange), no P LDS.
// Block = (b,h, 128-q tile), 4 waves; wave w owns q rows w*32..w*32+31.
// KV tiles of 64, double-buffered staging.
__global__ __launch_bounds__(256, 3) void attn_mfma(
        const ushort* __restrict__ qk, const ushort* __restrict__ vt,
        ushort* __restrict__ outp) {
    __shared__ ushort Ks[2][64 * 64];   // [key][d], XOR-8 swizzled
    __shared__ ushort Vts[2][64 * 64];  // [d][key], XOR-8 swizzled

    const int t = threadIdx.x;
    const int lane = t & 63;
    const int w = t >> 6;
    const int l32 = lane & 31;
    const int hi = lane >> 5;
    const int srow = lane >> 3;
    const int schunk = lane & 7;

    // XCD swizzle: 8 q-tiles of one bh land on one XCD, consecutively.
    const int bid = blockIdx.x;
    const int qt = (bid >> 3) & 7;
    const int bh = (bid & 7) + 8 * (bid >> 6);
    const int h = bh % Hh, b = bh / Hh;

    const size_t rs = 2 * Cdim;  // 1536
    const ushort* qbase = qk + (size_t)b * Nseq * rs + h * Dd;
    const ushort* kbase = qbase + Cdim;
    // vt is [768][16384]: row = h*64+d, col = b*1024 + n
    const ushort* vbase = vt + (size_t)(h * Dd) * LDV + (size_t)b * Nseq;

    // Q fragments in registers (pre-scaled by SCALE*log2e at gemm1).
    // B-op for S^T: lane holds Q[q=l32][d=kc*16+hi*8+j]
    short8 aq[4];
    {
        int q = qt * 128 + w * 32 + l32;
#pragma unroll
        for (int kc = 0; kc < 4; ++kc)
            aq[kc] = *(const short8*)&qbase[(size_t)q * rs + kc * 16 + hi * 8];
    }

    auto stage = [&](int kt64, int buf) {
#pragma unroll
        for (int i = 0; i < 2; ++i) {
            int r0 = (w * 2 + i) * 8;
            int row = r0 + srow;
            int cs = (schunk ^ (row & 7)) * 8;
            gld16(&Ks[buf][r0 * 64], &kbase[(size_t)(kt64 * 64 + row) * rs + cs]);
            gld16(&Vts[buf][r0 * 64], &vbase[(size_t)row * LDV + kt64 * 64 + cs]);
        }
    };

    floatx16 o[2];
    o[0] = (floatx16)0.0f;
    o[1] = (floatx16)0.0f;
    float lsum = 0.f;

    stage(0, 0);
    for (int kt = 0; kt < Nseq / 64; ++kt) {
        __syncthreads();  // drains DMA for tile kt; guards buf reuse
        if (kt + 1 < Nseq / 64) stage(kt + 1, (kt + 1) & 1);
        const ushort* Kb = Ks[kt & 1];
        const ushort* Vb = Vts[kt & 1];

        // S^T = K Q^T : st[km] reg r = S^T[key=km*32+(r&3)+8*(r>>2)+4*hi][q=l32]
        floatx16 st[2];
        st[0] = (floatx16)0.0f;
        st[1] = (floatx16)0.0f;
#pragma unroll
        for (int kc = 0; kc < 4; ++kc) {
            const int cs = ((kc * 2 + hi) ^ (l32 & 7)) * 8;
            short8 ak0 = *(const short8*)&Kb[l32 * 64 + cs];
            short8 ak1 = *(const short8*)&Kb[(32 + l32) * 64 + cs];
            st[0] = __builtin_amdgcn_mfma_f32_32x32x16_bf16(ak0, aq[kc], st[0], 0, 0, 0);
            st[1] = __builtin_amdgcn_mfma_f32_32x32x16_bf16(ak1, aq[kc], st[1], 0, 0, 0);
        }

#pragma unroll
        for (int km = 0; km < 2; ++km) {
            // p = 2^s (Q pre-scaled by log2e); all 16 values belong to q=l32.
            // key(p[r]) = km*32 + (r&3) + 8*(r>>2) + 4*hi
            float p[16];
#pragma unroll
            for (int r = 0; r < 16; ++r) p[r] = fexp2(st[km][r]);
            lsum += (((p[0] + p[1]) + (p[2] + p[3])) +
                     ((p[4] + p[5]) + (p[6] + p[7]))) +
                    (((p[8] + p[9]) + (p[10] + p[11])) +
                     ((p[12] + p[13]) + (p[14] + p[15])));
            // pack consecutive-key pairs: c[i] = bf16(p[2i]) | bf16(p[2i+1])<<16
            // keys(c[i]): i=0:(0,1)+4hi  1:(2,3)+4hi  2:(8,9)+4hi  3:(10,11)+4hi
            //             4:(16,17)+4hi 5:(18,19)+4hi 6:(24,25)+4hi 7:(26,27)+4hi
            uint c[8];
#pragma unroll
            for (int i = 0; i < 8; ++i) {
                union { __hip_bfloat162 h2; uint u; } cv;
                cv.h2 = __float22bfloat162_rn(make_float2(p[2 * i], p[2 * i + 1]));
                c[i] = cv.u;
            }
            // half-wave exchange: A-frag word jw holds keys (8hi+2jw, 8hi+2jw+1)
            // lo lane: [c0,c1, partner c0, partner c1]
            // hi lane: [partner c2, partner c3, c2, c3]
            uint wd[8];
#if __has_builtin(__builtin_amdgcn_permlane32_swap)
            uint2v r02 = __builtin_amdgcn_permlane32_swap(c[0], c[2], false, false);
            uint2v r13 = __builtin_amdgcn_permlane32_swap(c[1], c[3], false, false);
            uint2v r46 = __builtin_amdgcn_permlane32_swap(c[4], c[6], false, false);
            uint2v r57 = __builtin_amdgcn_permlane32_swap(c[5], c[7], false, false);
            wd[0] = r02.x; wd[2] = r02.y;
            wd[1] = r13.x; wd[3] = r13.y;
            wd[4] = r46.x; wd[6] = r46.y;
            wd[5] = r57.x; wd[7] = r57.y;
#else
            uint x0 = __shfl_xor(c[0], 32), x1 = __shfl_xor(c[1], 32);
            uint x2 = __shfl_xor(c[2], 32), x3 = __shfl_xor(c[3], 32);
            uint x4 = __shfl_xor(c[4], 32), x5 = __shfl_xor(c[5], 32);
            uint x6 = __shfl_xor(c[6], 32), x7 = __shfl_xor(c[7], 32);
            wd[0] = hi ? x2 : c[0]; wd[1] = hi ? x3 : c[1];
            wd[2] = hi ? c[2] : x0; wd[3] = hi ? c[3] : x1;
            wd[4] = hi ? x6 : c[4]; wd[5] = hi ? x7 : c[5];
            wd[6] = hi ? c[6] : x4; wd[7] = hi ? c[7] : x5;
#endif
            union { uint u[4]; short8 s; } af0, af1;
            af0.u[0] = wd[0]; af0.u[1] = wd[1]; af0.u[2] = wd[2]; af0.u[3] = wd[3];
            af1.u[0] = wd[4]; af1.u[1] = wd[5]; af1.u[2] = wd[6]; af1.u[3] = wd[7];

            // O[q][d] += P V : B-op = V[key][d=l32+dblk*32] from Vts[d][key]
#pragma unroll
            for (int dblk = 0; dblk < 2; ++dblk) {
                const int row = dblk * 32 + l32;
#pragma unroll
                for (int ks = 0; ks < 2; ++ks) {
                    const int ch = ((km * 4 + ks * 2 + hi) ^ (l32 & 7)) * 8;
                    short8 bv = *(const short8*)&Vb[row * 64 + ch];
                    o[dblk] = __builtin_amdgcn_mfma_f32_32x32x16_bf16(
                        ks ? af1.s : af0.s, bv, o[dblk], 0, 0, 0);
                }
            }
        }
    }

    // full row-sum: partner half-wave holds the other 32 keys per tile
    float lf = lsum + __shfl_xor(lsum, 32);
    float linv = __builtin_amdgcn_rcpf(lf);

    // O C-layout: col = d = l32 (+dblk*32), row = q = (r&3)+8*(r>>2)+4*hi
    const int qg0 = qt * 128 + w * 32;
#pragma unroll
    for (int r = 0; r < 16; ++r) {
        int rowq = (r & 3) + 8 * (r >> 2) + 4 * hi;
        float li = __shfl(linv, rowq);
        int q = qg0 + rowq;
#pragma unroll
        for (int dblk = 0; dblk < 2; ++dblk) {
            int d = dblk * 32 + l32;
            outp[((size_t)(b * Nseq + q)) * Cdim + h * Dd + d] =
                f2bs(o[dblk][r] * li);
        }
    }
}

extern "C" void kernel_launch(void* const* d_in, const int* in_sizes, int n_in,
                              void* d_out, int out_size, void* d_ws, size_t ws_size,
                              hipStream_t stream) {
    const float* x      = (const float*)d_in[0];
    const float* qkv_w  = (const float*)d_in[1];
    const float* qkv_b  = (const float*)d_in[2];
    const float* proj_w = (const float*)d_in[3];
    const float* proj_b = (const float*)d_in[4];
    float* out = (float*)d_out;

    const int M = Bsz * Nseq;  // 16384
    ushort* xb    = (ushort*)d_ws;                        // [16384x768]
    ushort* qk    = xb + (size_t)M * Cdim;                // [16384x1536]
    ushort* vtbuf = qk + (size_t)M * 2 * Cdim;            // [768][16384]
    ushort* wqkvb = vtbuf + (size_t)Cdim * M;             // [2304x768]
    ushort* wprjb = wqkvb + (size_t)3 * Cdim * Cdim;      // [768x768]
    ushort* attnout = xb;  // xb dead after VT-gemm

    // 0) fp32 -> bf16 pack
    pack_bf16<<<14592, 256, 0, stream>>>(x, qkv_w, proj_w, xb, wqkvb, wprjb);
    // 1a) QK GEMM: X @ Wqk^T -> qk [16384x1536]; Q cols pre-scaled by QSC
    gemm_nt_mfma<ushort><<<dim3(12, 128), 256, 0, stream>>>(
        xb, wqkvb, qkv_b, qk, 2 * Cdim, M, 2 * Cdim, Cdim, 0, Cdim, QSC);
    // 1b) VT GEMM: Wv @ X^T -> vt [768][16384], bias per row, coalesced
    gemm_nt_mfma<ushort><<<dim3(128, 6), 256, 0, stream>>>(
        wqkvb + (size_t)2 * Cdim * Cdim, xb, qkv_b + 2 * Cdim, vtbuf,
        M, Cdim, M, Cdim, 1, 0, 1.0f);
    // 2) attention
    attn_mfma<<<Bsz * Hh * (Nseq / 128), 256, 0, stream>>>(qk, vtbuf, attnout);
    // 3) projection -> fp32 out
    gemm_nt_mfma<float><<<dim3(6, 128), 256, 0, stream>>>(
        attnout, wprjb, proj_b, out, Cdim, M, Cdim, Cdim, 0, 0, 1.0f);
}